// Round 1
// 173.830 us; speedup vs baseline: 1.0124x; 1.0124x over previous
//
#include <hip/hip_runtime.h>
#include <hip/hip_bf16.h>

// Problem constants
#define BB 256
#define TT 256
#define CC 384
#define HSS 64

typedef __bf16 bf16_t;
typedef bf16_t bf16x8 __attribute__((ext_vector_type(8)));
typedef bf16_t bf16x4 __attribute__((ext_vector_type(4)));
typedef float f32x4 __attribute__((ext_vector_type(4)));

__device__ __forceinline__ f32x4 mfma16(bf16x8 a, bf16x8 b, f32x4 c) {
    return __builtin_amdgcn_mfma_f32_16x16x32_bf16(a, b, c, 0, 0, 0);
}

__device__ __forceinline__ bf16x8 cvt8(float4 a, float4 b) {
    bf16x8 r;
    r[0] = (bf16_t)a.x; r[1] = (bf16_t)a.y; r[2] = (bf16_t)a.z; r[3] = (bf16_t)a.w;
    r[4] = (bf16_t)b.x; r[5] = (bf16_t)b.y; r[6] = (bf16_t)b.z; r[7] = (bf16_t)b.w;
    return r;
}

// async global->LDS, 16B per lane; LDS dest wave-uniform base, HW scatters
// lane i to base + i*16. No VGPR destination -> immune to register-budget
// serialization (the r2-r4 killer).
typedef __attribute__((address_space(3))) unsigned int lds_uint_t;
typedef const __attribute__((address_space(1))) unsigned int glb_uint_t;
__device__ __forceinline__ void async_cp16(const void* g, void* lds_uniform) {
    __builtin_amdgcn_global_load_lds((glb_uint_t*)g, (lds_uint_t*)lds_uniform, 16, 0, 0);
}

// ---------------- Kernel 0: W -> WtG, bf16, transposed + pre-swizzled ----------------
// WtG[kc][n][pc][e]: kc = 64-wide K-chunk (0..5), n = 0..191 output feature,
// pc = c ^ (n&7) (16B chunks, c=kin>>3), e = 0..7. Linear-DMA-stageable +
// conflict-free ds_read_b128 B-frags.
__global__ void prep_w(const float* __restrict__ Wq, const float* __restrict__ Wk,
                       const float* __restrict__ Wv, bf16_t* __restrict__ WtG) {
    int idx = blockIdx.x * 256 + threadIdx.x;
    if (idx >= 192 * 384) return;
    int n = idx / 384, k = idx % 384;
    const float* W = (n < 64) ? Wq : (n < 128) ? Wk : Wv;
    float val = W[k * 64 + (n & 63)];
    int kc = k >> 6, kin = k & 63;
    int c = kin >> 3, e = k & 7;
    int pc = c ^ (n & 7);
    WtG[kc * 12288 + n * 64 + pc * 8 + e] = (bf16_t)val;
}

// ---------------- Kernel 1: fully fused head (QKV + causal attention) ----------------
// One block per batch (grid 256 = 1 block/CU). r6 change: 1024 thr = 16 waves
// (was 512/8) — wave w owns exactly query tile w. LDS still caps us at
// 1 block/CU, so the only way to raise the 20.8% occupancy (the latency-bound
// signature: MfmaUtil 5.9%, VALUBusy 8.2%, HBM 11%) is more waves per block:
// 2 -> 4 waves/SIMD. Per-wave acc halves (24 -> 12 f32x4, −48 VGPR) so the
// 128-VGPR/4-wave budget holds. Phase A is the same double-buffered pipeline:
// each iter issues DMA(kc+1) + x-loads(kc+1) right after the barrier, then
// MFMAs on chunk kc. K/V go register->LDS (swizzled, round-5-proven reader
// layouts); Q transposes via the per-wave bounce. Phase B unchanged per-tile.
__global__ __attribute__((amdgpu_flat_work_group_size(1024, 1024),
                          amdgpu_waves_per_eu(4, 4)))
void head_fused(
    const float* __restrict__ x, const bf16_t* __restrict__ WtG,
    const float* __restrict__ bq, const float* __restrict__ bk, const float* __restrict__ bv,
    float* __restrict__ out) {

    __shared__ bf16_t Wl[2][12288];               // 2 x 24 KB: W chunk double-buffer
    __shared__ uint4 Ksw[2048];                   // 32 KB: K [256][64] swizzled
    __shared__ uint4 Vsw[2048];                   // 32 KB: V^T [64][256] swizzled
    __shared__ __align__(16) bf16_t Pb[16 * 640]; // 20 KB: per-wave Q/P bounce

    int b = blockIdx.x, tid = threadIdx.x;
    int w = tid >> 6, l = tid & 63, lr = l & 15, lq = l >> 4;
    int Mt = w;                                   // this wave's single query tile

    // bias fragments (feature = nt*16+lr)
    float bqv[4], bkv[4], bvv[4];
#pragma unroll
    for (int nt = 0; nt < 4; nt++) {
        bqv[nt] = bq[nt * 16 + lr];
        bkv[nt] = bk[nt * 16 + lr];
        bvv[nt] = bv[nt * 16 + lr];
    }

    const float* xr = x + ((size_t)b * TT + Mt * 16 + lr) * CC;

    // ======== Phase A: QKV GEMM, 6-stage double-buffered pipeline ========
    f32x4 acc[12];
#pragma unroll
    for (int i = 0; i < 12; i++) acc[i] = (f32x4){0.f, 0.f, 0.f, 0.f};

    float4 xf[2][2];                              // in-flight x [t][half]

    // 24 KB W chunk = 24 x 1 KB groups; wave w stages group w, waves 0..7
    // additionally stage groups 16..23. Wave-uniform LDS base per call.
#define DMA_CHUNK(kc, buf)                                                   \
    {                                                                        \
        const bf16_t* _src = WtG + (kc) * 12288;                             \
        int cb0 = w * 64;                                                    \
        async_cp16(_src + (size_t)(cb0 + l) * 8,                             \
                   &Wl[buf][(size_t)cb0 * 8]);                               \
        if (w < 8) {                                                         \
            int cb1 = (16 + w) * 64;                                         \
            async_cp16(_src + (size_t)(cb1 + l) * 8,                         \
                       &Wl[buf][(size_t)cb1 * 8]);                           \
        }                                                                    \
    }
#define LOAD_X(kc)                                                           \
    {                                                                        \
        _Pragma("unroll")                                                    \
        for (int t = 0; t < 2; t++) {                                        \
            const float* xp = xr + (kc) * 64 + t * 32 + lq * 8;              \
            xf[t][0] = *(const float4*)xp;                                   \
            xf[t][1] = *(const float4*)(xp + 4);                             \
        }                                                                    \
    }

    DMA_CHUNK(0, 0);
    LOAD_X(0);

#pragma unroll
    for (int kc = 0; kc < 6; kc++) {
        __syncthreads();   // drains DMA(kc)+x(kc); retires reads of buf[(kc+1)&1]
        // convert this chunk's x (already in regs) before xf is reused
        bf16x8 af[2];
#pragma unroll
        for (int t = 0; t < 2; t++) af[t] = cvt8(xf[t][0], xf[t][1]);
        if (kc < 5) {                             // prefetch next stage
            DMA_CHUNK(kc + 1, (kc + 1) & 1);
            LOAD_X(kc + 1);
        }
        const bf16_t* buf = Wl[kc & 1];
#pragma unroll
        for (int nt = 0; nt < 12; nt++) {
            const bf16_t* wl = buf + (size_t)(nt * 16 + lr) * 64;
#pragma unroll
            for (int t = 0; t < 2; t++) {
                int pc = (t * 4 + lq) ^ (lr & 7);
                bf16x8 bfrag = *(const bf16x8*)(wl + pc * 8);
                acc[nt] = mfma16(af[t], bfrag, acc[nt]);
            }
        }
    }
#undef DMA_CHUNK
#undef LOAD_X

    // ======== K and V^T: registers -> swizzled LDS (with bias) ========
    bf16_t* KswB = (bf16_t*)Ksw;
    bf16_t* VswB = (bf16_t*)Vsw;
#pragma unroll
    for (int nt = 4; nt < 8; nt++) {            // K[s][d], chunk c at c^(s&7)
        int d = (nt - 4) * 16 + lr;
#pragma unroll
        for (int r = 0; r < 4; r++) {
            int s = Mt * 16 + lq * 4 + r;
            KswB[s * 64 + ((d >> 3) ^ (s & 7)) * 8 + (d & 7)] =
                (bf16_t)(acc[nt][r] + bkv[nt - 4]);
        }
    }
#pragma unroll
    for (int nt = 8; nt < 12; nt++) {           // V^T[d][t], chunk c at (c&~7)|((c^d)&7)
        int d = (nt - 8) * 16 + lr;
        int t0 = Mt * 16 + lq * 4;
        int c = t0 >> 3;
        bf16x4 pk;
#pragma unroll
        for (int r = 0; r < 4; r++) pk[r] = (bf16_t)(acc[nt][r] + bvv[nt - 8]);
        *(bf16x4*)(VswB + d * 256 + ((c & ~7) | ((c ^ d) & 7)) * 8 + (t0 & 7)) = pk;
    }
    __syncthreads();                            // K/V visible to all waves

    // ======== Phase B: causal attention, one tile per wave ========
    const float scale2 = 0.125f * 1.4426950408889634f; // HS^-0.5 * log2(e)
    bf16_t* Pw = Pb + w * 640;                  // wave-private bounce (16 x stride-40)

    int R0 = Mt * 16;
    int tg = R0 + lr;                           // this lane's query row (C col)
    int ktm = Mt >> 1;                          // causal bound on 32-key chunks

    // -- Q transpose via bounce: C-frag(d=nt*16+lr, t=lq*4+r) -> B-frag(t=lr, d=lq*8+j)
    bf16x8 qf[2];
#pragma unroll
    for (int hh = 0; hh < 2; hh++) {            // d-halves 0..31 / 32..63
#pragma unroll
        for (int u = 0; u < 2; u++) {
            int nt = 2 * hh + u;
#pragma unroll
            for (int r = 0; r < 4; r++)
                Pw[(lq * 4 + r) * 40 + u * 16 + lr] =
                    (bf16_t)(acc[nt][r] + bqv[nt]);
        }
        qf[hh] = *(const bf16x8*)(Pw + lr * 40 + lq * 8);
    }

    f32x4 oacc[4] = {};
    float sum = 0.f;
#pragma unroll
    for (int kt = 0; kt < 8; kt++) {
        if (kt <= ktm) {                        // wave-uniform causal skip
#pragma unroll
            for (int u = 0; u < 2; u++) {
                int nt = kt * 2 + u;
                int s = nt * 16 + lr;
                const uint4* krow = Ksw + s * 8;
                bf16x8 k0 = __builtin_bit_cast(bf16x8, krow[lq ^ (s & 7)]);
                bf16x8 k1 = __builtin_bit_cast(bf16x8, krow[(4 + lq) ^ (s & 7)]);
                f32x4 a = {0.f, 0.f, 0.f, 0.f};
                a = mfma16(k0, qf[0], a);       // S^T: col=t(lr), row=s(lq*4+r)
                a = mfma16(k1, qf[1], a);
                bf16x4 pk;
#pragma unroll
                for (int r = 0; r < 4; r++) {
                    int sg = nt * 16 + lq * 4 + r;
                    float p = (sg <= tg) ? exp2f(a[r] * scale2) : 0.f;
                    sum += p;
                    pk[r] = (bf16_t)p;
                }
                *(bf16x4*)(Pw + lr * 40 + u * 16 + lq * 4) = pk;
            }
            // P^T B-frag: row t=lr, k = s-local = lq*8+j
            bf16x8 pf = *(const bf16x8*)(Pw + lr * 40 + lq * 8);
#pragma unroll
            for (int dt = 0; dt < 4; dt++) {
                int d = dt * 16 + lr;
                int cc = kt * 4 + lq;
                bf16x8 vf = __builtin_bit_cast(bf16x8,
                    Vsw[d * 32 + ((cc & ~7) | ((cc ^ d) & 7))]);
                // O^T = V^T . P^T: col=t(lr), row=d-local(lq*4+r)
                oacc[dt] = mfma16(vf, pf, oacc[dt]);
            }
        }
    }

    // denominator for query t=lr: partials live in lanes {lr,+16,+32,+48}
    sum += __shfl_xor(sum, 16);
    sum += __shfl_xor(sum, 32);
    float inv = 1.0f / sum;

    // epilogue: O^T frag -> coalesced float4 stores (d = dt*16+lq*4..+3)
    float* orow = out + ((size_t)b * TT + R0 + lr) * HSS;
#pragma unroll
    for (int dt = 0; dt < 4; dt++) {
        float4 o;
        o.x = oacc[dt][0] * inv;
        o.y = oacc[dt][1] * inv;
        o.z = oacc[dt][2] * inv;
        o.w = oacc[dt][3] * inv;
        *(float4*)(orow + dt * 16 + lq * 4) = o;
    }
}

extern "C" void kernel_launch(void* const* d_in, const int* in_sizes, int n_in,
                              void* d_out, int out_size, void* d_ws, size_t ws_size,
                              hipStream_t stream) {
    const float* x  = (const float*)d_in[0];
    const float* Wq = (const float*)d_in[1];
    const float* bq = (const float*)d_in[2];
    const float* Wk = (const float*)d_in[3];
    const float* bk = (const float*)d_in[4];
    const float* Wv = (const float*)d_in[5];
    const float* bv = (const float*)d_in[6];
    float* out = (float*)d_out;

    bf16_t* WtG = (bf16_t*)d_ws;               // 6*12288 bf16, swizzled

    prep_w<<<288, 256, 0, stream>>>(Wq, Wk, Wv, WtG);
    head_fused<<<BB, 1024, 0, stream>>>(x, WtG, bq, bk, bv, out);
}